// Round 7
// baseline (98.031 us; speedup 1.0000x reference)
//
#include <hip/hip_runtime.h>

#define NB 2
#define CIN 256
#define HH 64
#define WW 64
#define CCMP 64
#define HO 128
#define WO 128

// padded comp layout: [n][c][66][66], interior at (+1,+1)
#define CPLD 66
#define CPCH (CPLD * CPLD)          // 4356
#define CPIMG (CCMP * CPCH)         // 278784
#define CPTOT (NB * CPIMG)          // 557568 floats

// ws layout (floats)
#define OFF_OFFB  (CPTOT)                       // 557568
#define OFF_KERB  (OFF_OFFB + 65536)            // 623104
#define OFF_WTS   (OFF_KERB + 204800)           // 827904
#define OFF_WCT   (OFF_WTS + 819200)            // 1647104
#define OFF_W2T   (OFF_WCT + 16384)             // 1663488  (w2t: 33*9*64 = 19008)

// ---------------- k0: zero only the halo of comp_pad (260 elems/plane) ----------------
__global__ __launch_bounds__(256) void k0_halo(float* __restrict__ comp_pad) {
  int img = blockIdx.x;            // 128 blocks: n*CCMP + c
  float* p = comp_pad + (size_t)img * CPCH;
  for (int i = threadIdx.x; i < 260; i += 256) {
    if (i < 66)       p[i] = 0.f;
    else if (i < 132) p[65 * CPLD + (i - 66)] = 0.f;
    else if (i < 196) p[(i - 131) * CPLD] = 0.f;
    else              p[(i - 195) * CPLD + 65] = 0.f;
  }
}

// ---------------- k0t: transpose weights once ----------------
// wct[c][oc]   (64*256=16384)  from w_comp[oc][c]
// w2t[oc][tap][c] (33*9*64=19008) from w_off/w_ker [oc][c][tap]
__global__ __launch_bounds__(256) void k0t_prep(const float* __restrict__ w_comp,
                                                const float* __restrict__ w_off,
                                                const float* __restrict__ w_ker,
                                                float* __restrict__ wct,
                                                float* __restrict__ w2t) {
  int t = blockIdx.x * 256 + threadIdx.x;   // 139 blocks -> 35584 threads
  if (t < 16384) {
    int c = t >> 6, oc = t & 63;
    wct[t] = w_comp[oc * 256 + c];
  }
  int u = t - 16384;
  if (u >= 0 && u < 33 * 9 * 64) {
    int oc = u / 576;
    int rem = u % 576;
    int tap = rem >> 6;
    int c = rem & 63;
    w2t[u] = (oc < 8) ? w_off[(oc * 64 + c) * 9 + tap]
                      : w_ker[((oc - 8) * 64 + c) * 9 + tap];
  }
}

// ---------------- k1: 1x1 conv x(2,256,64,64) -> comp_pad interior ----------------
// 256 blocks: (n, ccg of 8, hq of 16); 8 oc/thread; weights via 2 float4 broadcast loads.
__global__ __launch_bounds__(256) void k1_comp(const float* __restrict__ x,
                                               const float* __restrict__ wct,
                                               const float* __restrict__ bc,
                                               float* __restrict__ comp_pad) {
  int b = blockIdx.x;
  int n = b >> 7;
  int ccg = (b >> 4) & 7;
  int hq = b & 15;
  int hsub = threadIdx.x >> 6;
  int w = threadIdx.x & 63;
  int h = hq * 4 + hsub;
  float acc[8];
#pragma unroll
  for (int j = 0; j < 8; ++j) acc[j] = bc[ccg * 8 + j];
  const float* xp = x + ((size_t)(n * CIN) * HH + h) * WW + w;
  const float4* wc4 = (const float4*)(wct + ccg * 8);   // + c*16 float4s per c
#pragma unroll 4
  for (int c = 0; c < CIN; ++c) {
    float xv = xp[(size_t)c * HH * WW];
    float4 w0 = wc4[c * 16];
    float4 w1 = wc4[c * 16 + 1];
    acc[0] += xv * w0.x; acc[1] += xv * w0.y; acc[2] += xv * w0.z; acc[3] += xv * w0.w;
    acc[4] += xv * w1.x; acc[5] += xv * w1.y; acc[6] += xv * w1.z; acc[7] += xv * w1.w;
  }
#pragma unroll
  for (int j = 0; j < 8; ++j)
    comp_pad[(size_t)n * CPIMG + (size_t)(ccg * 8 + j) * CPCH + (h + 1) * CPLD + (w + 1)] = acc[j];
}

// ------------- k2: fused 3x3 convs comp_pad -> off(8ch) + ker(25ch) -------------
// 544 blocks: (n, ocp of 17, hq of 16). 2 oc/thread; weights via aligned float4 from w2t.
__global__ __launch_bounds__(256) void k2_conv3(const float* __restrict__ comp_pad,
                                                const float* __restrict__ w2t,
                                                const float* __restrict__ b_off,
                                                const float* __restrict__ b_ker,
                                                float* __restrict__ offb,
                                                float* __restrict__ kerb) {
  int b = blockIdx.x;
  int n = b / (17 * 16);
  int r = b % (17 * 16);
  int ocp = r / 16;
  int hq = r % 16;
  int hsub = threadIdx.x >> 6;
  int w = threadIdx.x & 63;
  int h = hq * 4 + hsub;

  int oc0 = ocp * 2;
  int oc1 = (oc0 + 1 < 33) ? oc0 + 1 : 32;   // last block: duplicate oc 32 (benign)
  const float* wp0 = w2t + (size_t)oc0 * 576;   // [tap][c]
  const float* wp1 = w2t + (size_t)oc1 * 576;
  float a0 = (oc0 < 8) ? b_off[oc0] : b_ker[oc0 - 8];
  float a1 = (oc1 < 8) ? b_off[oc1] : b_ker[oc1 - 8];

  const float* base = comp_pad + (size_t)n * CPIMG + h * CPLD + w;

  for (int cb = 0; cb < CCMP; cb += 4) {
    float t[4][9];
#pragma unroll
    for (int cc = 0; cc < 4; ++cc) {
      const float* p = base + (size_t)(cb + cc) * CPCH;
#pragma unroll
      for (int dy = 0; dy < 3; ++dy)
#pragma unroll
        for (int dx = 0; dx < 3; ++dx)
          t[cc][dy * 3 + dx] = p[dy * CPLD + dx];
    }
#pragma unroll
    for (int tap = 0; tap < 9; ++tap) {
      float4 w40 = *(const float4*)(wp0 + tap * 64 + cb);
      float4 w41 = *(const float4*)(wp1 + tap * 64 + cb);
      a0 += t[0][tap] * w40.x + t[1][tap] * w40.y + t[2][tap] * w40.z + t[3][tap] * w40.w;
      a1 += t[0][tap] * w41.x + t[1][tap] * w41.y + t[2][tap] * w41.z + t[3][tap] * w41.w;
    }
  }

  int pos = h * WW + w;
  if (oc0 < 8) offb[(size_t)(n * 8 + oc0) * 4096 + pos] = a0;
  else         kerb[(size_t)(n * 25 + (oc0 - 8)) * 4096 + pos] = a0;
  if (oc1 < 8) offb[(size_t)(n * 8 + oc1) * 4096 + pos] = a1;
  else         kerb[(size_t)(n * 25 + (oc1 - 8)) * 4096 + pos] = a1;
}

// ---------------- k3: softmax over the 25 ker channels, in place ----------------
__global__ void k3_softmax(float* __restrict__ kerb) {
  int t = blockIdx.x * 256 + threadIdx.x;  // 8192 threads
  int n = t >> 12;
  int pos = t & 4095;
  float v[25];
  float mx = -1e30f;
#pragma unroll
  for (int k = 0; k < 25; ++k) {
    v[k] = kerb[(size_t)(n * 25 + k) * 4096 + pos];
    mx = fmaxf(mx, v[k]);
  }
  float s = 0.f;
#pragma unroll
  for (int k = 0; k < 25; ++k) { v[k] = expf(v[k] - mx); s += v[k]; }
  float inv = 1.f / s;
#pragma unroll
  for (int k = 0; k < 25; ++k) kerb[(size_t)(n * 25 + k) * 4096 + pos] = v[k] * inv;
}

// ------- k4: bilinear-sample mask at offsets -> wts[n][h][pq][k][w] (w fastest) -------
__global__ void k4_wts(const float* __restrict__ offb, const float* __restrict__ mask,
                       float* __restrict__ wts) {
  int t = blockIdx.x * 256 + threadIdx.x;   // 32768 threads: (n, ho, wo)
  int n = t >> 14;
  int r = t & 16383;
  int ho = r >> 7;
  int wo = r & 127;
  int h = ho >> 1, p = ho & 1, w = wo >> 1, q = wo & 1;
  int pq = p * 2 + q;
  float offx = offb[((size_t)(n * 8 + pq) * HH + h) * WW + w];
  float offy = offb[((size_t)(n * 8 + 4 + pq) * HH + h) * WW + w];
  float ix = fminf(fmaxf((float)w + offx, 0.f), 63.f);
  float iy = fminf(fmaxf((float)h + offy, 0.f), 63.f);
  float x0f = floorf(ix), y0f = floorf(iy);
  float fx = ix - x0f, fy = iy - y0f;
  int x0 = (int)x0f, y0 = (int)y0f;
  int x1 = min(x0 + 1, 63), y1 = min(y0 + 1, 63);
  float w00 = (1.f - fx) * (1.f - fy), w01 = fx * (1.f - fy);
  float w10 = (1.f - fx) * fy,         w11 = fx * fy;
  float* wp = wts + (((size_t)(n * HH + h) * 4 + pq) * 25) * 64 + w;
#pragma unroll
  for (int k = 0; k < 25; ++k) {
    const float* mp = mask + (size_t)(n * 25 + k) * 4096;
    wp[k * 64] = mp[y0 * 64 + x0] * w00 + mp[y0 * 64 + x1] * w01 +
                 mp[y1 * 64 + x0] * w10 + mp[y1 * 64 + x1] * w11;
  }
}

// -------- k5: out[n,c,2h+p,2w+q] = sum_k wt·x; wts reads now lane-coalesced --------
__global__ __launch_bounds__(256) void k5_out(const float* __restrict__ x,
                                              const float* __restrict__ wts,
                                              float* __restrict__ out) {
  int b = blockIdx.x;       // 1024 blocks: n(2) * h(64) * cg(8)
  int n = b >> 9;
  int r = b & 511;
  int h = r >> 3;
  int cg = r & 7;
  int wave = threadIdx.x >> 6;
  int w = threadIdx.x & 63;
  int c0 = cg * 32 + wave * 8;   // 8 channels per wave

#pragma unroll
  for (int half = 0; half < 2; ++half) {
    // hoist 50 weights (pq = 2*half, 2*half+1): coalesced loads, stride 64 floats
    const float* wbase = wts + (((size_t)(n * HH + h) * 4 + 2 * half) * 25) * 64 + w;
    float wt[50];
#pragma unroll
    for (int i = 0; i < 50; ++i) wt[i] = wbase[i * 64];

    for (int ci = 0; ci < 8; ++ci) {
      int c = c0 + ci;
      const float* xc = x + (size_t)(n * CIN + c) * HH * WW;
      float a0 = 0.f, a1 = 0.f;
#pragma unroll
      for (int dy = 0; dy < 5; ++dy) {
        int rr = h + dy - 2;
        bool rok = (unsigned)rr < (unsigned)HH;
        const float* xr = xc + rr * WW;
#pragma unroll
        for (int dx = 0; dx < 5; ++dx) {
          int cc = w + dx - 2;
          float xv = (rok && (unsigned)cc < (unsigned)WW) ? xr[cc] : 0.f;
          int k = dy * 5 + dx;
          a0 += wt[k] * xv;
          a1 += wt[25 + k] * xv;
        }
      }
      float2* o = (float2*)(out + ((size_t)(n * CIN + c) * HO + 2 * h + half) * WO + 2 * w);
      *o = make_float2(a0, a1);
    }
  }
}

extern "C" void kernel_launch(void* const* d_in, const int* in_sizes, int n_in,
                              void* d_out, int out_size, void* d_ws, size_t ws_size,
                              hipStream_t stream) {
  const float* x      = (const float*)d_in[0];
  const float* w_comp = (const float*)d_in[1];
  const float* b_comp = (const float*)d_in[2];
  const float* w_off  = (const float*)d_in[3];
  const float* b_off  = (const float*)d_in[4];
  const float* w_ker  = (const float*)d_in[5];
  const float* b_ker  = (const float*)d_in[6];
  float* out = (float*)d_out;

  float* ws       = (float*)d_ws;
  float* comp_pad = ws;
  float* offb     = ws + OFF_OFFB;
  float* kerb     = ws + OFF_KERB;
  float* wts      = ws + OFF_WTS;
  float* wct      = ws + OFF_WCT;
  float* w2t      = ws + OFF_W2T;

  k0_halo<<<NB * CCMP, 256, 0, stream>>>(comp_pad);
  k0t_prep<<<139, 256, 0, stream>>>(w_comp, w_off, w_ker, wct, w2t);
  k1_comp<<<256, 256, 0, stream>>>(x, wct, b_comp, comp_pad);
  k2_conv3<<<544, 256, 0, stream>>>(comp_pad, w2t, b_off, b_ker, offb, kerb);
  k3_softmax<<<32, 256, 0, stream>>>(kerb);
  k4_wts<<<128, 256, 0, stream>>>(offb, kerb, wts);
  k5_out<<<1024, 256, 0, stream>>>(x, wts, out);
}

// Round 8
// 78.182 us; speedup vs baseline: 1.2539x; 1.2539x over previous
//
#include <hip/hip_runtime.h>

#define NB 2
#define CIN 256
#define HH 64
#define WW 64
#define CCMP 64
#define HO 128
#define WO 128

// padded comp layout: [n][c][66][66], interior at (+1,+1)
#define CPLD 66
#define CPCH (CPLD * CPLD)          // 4356
#define CPIMG (CCMP * CPCH)         // 278784
#define CPTOT (NB * CPIMG)          // 557568 floats

// ws layout (floats)
#define OFF_OFFB  (CPTOT)
#define OFF_KERB  (OFF_OFFB + 65536)
#define OFF_WTS   (OFF_KERB + 204800)

// ---------------- k1: 1x1 conv -> comp_pad interior; also zeroes its halo ----------------
// 512 blocks: (n, ccg of 16, hq of 16); 4 oc/thread (2 waves/SIMD).
__global__ __launch_bounds__(256) void k1_comp(const float* __restrict__ x,
                                               const float* __restrict__ wc,
                                               const float* __restrict__ bc,
                                               float* __restrict__ comp_pad) {
  int b = blockIdx.x;
  int n = b >> 8;
  int ccg = (b >> 4) & 15;
  int hq = b & 15;
  int hsub = threadIdx.x >> 6;
  int w = threadIdx.x & 63;
  int h = hq * 4 + hsub;

  float acc[4];
#pragma unroll
  for (int j = 0; j < 4; ++j) acc[j] = bc[ccg * 4 + j];
  const float* xp = x + ((size_t)(n * CIN) * HH + h) * WW + w;
#pragma unroll 4
  for (int c = 0; c < CIN; ++c) {
    float xv = xp[(size_t)c * HH * WW];
#pragma unroll
    for (int j = 0; j < 4; ++j) acc[j] += xv * wc[(ccg * 4 + j) * CIN + c];
  }
  float* plane = comp_pad + (size_t)n * CPIMG + (size_t)(ccg * 4) * CPCH;
#pragma unroll
  for (int j = 0; j < 4; ++j)
    plane[(size_t)j * CPCH + (h + 1) * CPLD + (w + 1)] = acc[j];

  // halo zeroing for this block's 4 channel planes:
  // left/right cols for padded rows hq*4+1 .. hq*4+4  (32 threads)
  if (threadIdx.x < 32) {
    int ch = threadIdx.x >> 3;
    int rw = (threadIdx.x >> 1) & 3;
    int side = threadIdx.x & 1;
    plane[(size_t)ch * CPCH + (hq * 4 + rw + 1) * CPLD + side * 65] = 0.f;
  }
  if (hq == 0)
    for (int i = threadIdx.x; i < 4 * CPLD; i += 256)
      plane[(size_t)(i / CPLD) * CPCH + (i % CPLD)] = 0.f;               // top row
  if (hq == 15)
    for (int i = threadIdx.x; i < 4 * CPLD; i += 256)
      plane[(size_t)(i / CPLD) * CPCH + 65 * CPLD + (i % CPLD)] = 0.f;   // bottom row
}

// ------------- k2: fused 3x3 convs comp_pad -> off(8ch) + ker(25ch) -------------
// 544 blocks: (n, ocp of 17, hq of 16). 2 oc/thread; reg tile t[4][9]; uniform s_load weights.
__global__ __launch_bounds__(256) void k2_conv3(const float* __restrict__ comp_pad,
                                                const float* __restrict__ w_off,
                                                const float* __restrict__ b_off,
                                                const float* __restrict__ w_ker,
                                                const float* __restrict__ b_ker,
                                                float* __restrict__ offb,
                                                float* __restrict__ kerb) {
  int b = blockIdx.x;
  int n = b / (17 * 16);
  int r = b % (17 * 16);
  int ocp = r / 16;
  int hq = r % 16;
  int hsub = threadIdx.x >> 6;
  int w = threadIdx.x & 63;
  int h = hq * 4 + hsub;

  int oc0 = ocp * 2;
  int oc1 = (oc0 + 1 < 33) ? oc0 + 1 : 32;
  const float* wp0 = (oc0 < 8) ? (w_off + (size_t)oc0 * CCMP * 9)
                               : (w_ker + (size_t)(oc0 - 8) * CCMP * 9);
  const float* wp1 = (oc1 < 8) ? (w_off + (size_t)oc1 * CCMP * 9)
                               : (w_ker + (size_t)(oc1 - 8) * CCMP * 9);
  float a0 = (oc0 < 8) ? b_off[oc0] : b_ker[oc0 - 8];
  float a1 = (oc1 < 8) ? b_off[oc1] : b_ker[oc1 - 8];

  const float* base = comp_pad + (size_t)n * CPIMG + h * CPLD + w;

  for (int cb = 0; cb < CCMP; cb += 4) {
    float t[4][9];
#pragma unroll
    for (int cc = 0; cc < 4; ++cc) {
      const float* p = base + (size_t)(cb + cc) * CPCH;
#pragma unroll
      for (int dy = 0; dy < 3; ++dy)
#pragma unroll
        for (int dx = 0; dx < 3; ++dx)
          t[cc][dy * 3 + dx] = p[dy * CPLD + dx];
    }
#pragma unroll
    for (int cc = 0; cc < 4; ++cc)
#pragma unroll
      for (int k = 0; k < 9; ++k) {
        float tv = t[cc][k];
        a0 += tv * wp0[(cb + cc) * 9 + k];
        a1 += tv * wp1[(cb + cc) * 9 + k];
      }
  }

  int pos = h * WW + w;
  if (oc0 < 8) offb[(size_t)(n * 8 + oc0) * 4096 + pos] = a0;
  else         kerb[(size_t)(n * 25 + (oc0 - 8)) * 4096 + pos] = a0;
  if (oc1 < 8) offb[(size_t)(n * 8 + oc1) * 4096 + pos] = a1;
  else         kerb[(size_t)(n * 25 + (oc1 - 8)) * 4096 + pos] = a1;
}

// ------- k34: fused softmax + bilinear sample -> wts[n][h][pq][k][w] -------
// kerb holds RAW conv outputs; softmax is computed per corner in registers.
__global__ void k34_wts(const float* __restrict__ offb, const float* __restrict__ kerb,
                        float* __restrict__ wts) {
  int t = blockIdx.x * 256 + threadIdx.x;   // 32768 threads: (n, ho, wo)
  int n = t >> 14;
  int r = t & 16383;
  int ho = r >> 7;
  int wo = r & 127;
  int h = ho >> 1, p = ho & 1, w = wo >> 1, q = wo & 1;
  int pq = p * 2 + q;
  float offx = offb[((size_t)(n * 8 + pq) * HH + h) * WW + w];
  float offy = offb[((size_t)(n * 8 + 4 + pq) * HH + h) * WW + w];
  // align_corners=True + border clamp algebra: sample at (h+offy, w+offx)
  float ix = fminf(fmaxf((float)w + offx, 0.f), 63.f);
  float iy = fminf(fmaxf((float)h + offy, 0.f), 63.f);
  float x0f = floorf(ix), y0f = floorf(iy);
  float fx = ix - x0f, fy = iy - y0f;
  int x0 = (int)x0f, y0 = (int)y0f;
  int x1 = min(x0 + 1, 63), y1 = min(y0 + 1, 63);
  float g0 = (1.f - fx) * (1.f - fy), g1 = fx * (1.f - fy);
  float g2 = (1.f - fx) * fy,         g3 = fx * fy;

  const float* mb = kerb + (size_t)n * 25 * 4096;
  int c0 = y0 * 64 + x0, c1 = y0 * 64 + x1, c2 = y1 * 64 + x0, c3 = y1 * 64 + x1;

  float v0[25], v1[25], v2[25], v3[25];
#pragma unroll
  for (int k = 0; k < 25; ++k) {
    const float* mk = mb + (size_t)k * 4096;
    v0[k] = mk[c0]; v1[k] = mk[c1]; v2[k] = mk[c2]; v3[k] = mk[c3];
  }
  float m0 = v0[0], m1 = v1[0], m2 = v2[0], m3 = v3[0];
#pragma unroll
  for (int k = 1; k < 25; ++k) {
    m0 = fmaxf(m0, v0[k]); m1 = fmaxf(m1, v1[k]);
    m2 = fmaxf(m2, v2[k]); m3 = fmaxf(m3, v3[k]);
  }
  float S0 = 0.f, S1 = 0.f, S2 = 0.f, S3 = 0.f;
#pragma unroll
  for (int k = 0; k < 25; ++k) {
    v0[k] = expf(v0[k] - m0); S0 += v0[k];
    v1[k] = expf(v1[k] - m1); S1 += v1[k];
    v2[k] = expf(v2[k] - m2); S2 += v2[k];
    v3[k] = expf(v3[k] - m3); S3 += v3[k];
  }
  float f0 = g0 / S0, f1 = g1 / S1, f2 = g2 / S2, f3 = g3 / S3;

  float* wp = wts + (((size_t)(n * HH + h) * 4 + pq) * 25) * 64 + w;
#pragma unroll
  for (int k = 0; k < 25; ++k)
    wp[k * 64] = v0[k] * f0 + v1[k] * f1 + v2[k] * f2 + v3[k] * f3;
}

// -------- k5: out[n,c,2h+p,2w+q] = sum_k wt·x; coalesced wt hoist --------
__global__ __launch_bounds__(256) void k5_out(const float* __restrict__ x,
                                              const float* __restrict__ wts,
                                              float* __restrict__ out) {
  int b = blockIdx.x;       // 1024 blocks: n(2) * h(64) * cg(8)
  int n = b >> 9;
  int r = b & 511;
  int h = r >> 3;
  int cg = r & 7;
  int wave = threadIdx.x >> 6;
  int w = threadIdx.x & 63;
  int c0 = cg * 32 + wave * 8;   // 8 channels per wave

#pragma unroll
  for (int half = 0; half < 2; ++half) {
    const float* wbase = wts + (((size_t)(n * HH + h) * 4 + 2 * half) * 25) * 64 + w;
    float wt[50];
#pragma unroll
    for (int i = 0; i < 50; ++i) wt[i] = wbase[i * 64];

    for (int ci = 0; ci < 8; ++ci) {
      int c = c0 + ci;
      const float* xc = x + (size_t)(n * CIN + c) * HH * WW;
      float a0 = 0.f, a1 = 0.f;
#pragma unroll
      for (int dy = 0; dy < 5; ++dy) {
        int rr = h + dy - 2;
        bool rok = (unsigned)rr < (unsigned)HH;
        const float* xr = xc + rr * WW;
#pragma unroll
        for (int dx = 0; dx < 5; ++dx) {
          int cc = w + dx - 2;
          float xv = (rok && (unsigned)cc < (unsigned)WW) ? xr[cc] : 0.f;
          int k = dy * 5 + dx;
          a0 += wt[k] * xv;
          a1 += wt[25 + k] * xv;
        }
      }
      float2* o = (float2*)(out + ((size_t)(n * CIN + c) * HO + 2 * h + half) * WO + 2 * w);
      *o = make_float2(a0, a1);
    }
  }
}

extern "C" void kernel_launch(void* const* d_in, const int* in_sizes, int n_in,
                              void* d_out, int out_size, void* d_ws, size_t ws_size,
                              hipStream_t stream) {
  const float* x      = (const float*)d_in[0];
  const float* w_comp = (const float*)d_in[1];
  const float* b_comp = (const float*)d_in[2];
  const float* w_off  = (const float*)d_in[3];
  const float* b_off  = (const float*)d_in[4];
  const float* w_ker  = (const float*)d_in[5];
  const float* b_ker  = (const float*)d_in[6];
  float* out = (float*)d_out;

  float* ws       = (float*)d_ws;
  float* comp_pad = ws;
  float* offb     = ws + OFF_OFFB;
  float* kerb     = ws + OFF_KERB;   // raw conv output (softmax fused into k34)
  float* wts      = ws + OFF_WTS;

  k1_comp<<<512, 256, 0, stream>>>(x, w_comp, b_comp, comp_pad);
  k2_conv3<<<544, 256, 0, stream>>>(comp_pad, w_off, b_off, w_ker, b_ker, offb, kerb);
  k34_wts<<<128, 256, 0, stream>>>(offb, kerb, wts);
  k5_out<<<1024, 256, 0, stream>>>(x, wts, out);
}

// Round 9
// 73.395 us; speedup vs baseline: 1.3357x; 1.0652x over previous
//
#include <hip/hip_runtime.h>

#define NB 2
#define CIN 256
#define HH 64
#define WW 64
#define CCMP 64
#define HO 128
#define WO 128

// padded comp layout: [n][c][66][66], interior at (+1,+1)
#define CPLD 66
#define CPCH (CPLD * CPLD)          // 4356
#define CPIMG (CCMP * CPCH)         // 278784
#define CPTOT (NB * CPIMG)          // 557568 floats

// ws layout (floats)
#define OFF_OFFB  (CPTOT)
#define OFF_KERB  (OFF_OFFB + 65536)
#define OFF_WTS   (OFF_KERB + 204800)

// ---------------- k1: 1x1 conv -> comp_pad interior; also zeroes its halo ----------------
// 512 blocks: (n, ccg of 16, hq of 16); 4 oc/thread (2 waves/SIMD).
__global__ __launch_bounds__(256) void k1_comp(const float* __restrict__ x,
                                               const float* __restrict__ wc,
                                               const float* __restrict__ bc,
                                               float* __restrict__ comp_pad) {
  int b = blockIdx.x;
  int n = b >> 8;
  int ccg = (b >> 4) & 15;
  int hq = b & 15;
  int hsub = threadIdx.x >> 6;
  int w = threadIdx.x & 63;
  int h = hq * 4 + hsub;

  float acc[4];
#pragma unroll
  for (int j = 0; j < 4; ++j) acc[j] = bc[ccg * 4 + j];
  const float* xp = x + ((size_t)(n * CIN) * HH + h) * WW + w;
#pragma unroll 4
  for (int c = 0; c < CIN; ++c) {
    float xv = xp[(size_t)c * HH * WW];
#pragma unroll
    for (int j = 0; j < 4; ++j) acc[j] += xv * wc[(ccg * 4 + j) * CIN + c];
  }
  float* plane = comp_pad + (size_t)n * CPIMG + (size_t)(ccg * 4) * CPCH;
#pragma unroll
  for (int j = 0; j < 4; ++j)
    plane[(size_t)j * CPCH + (h + 1) * CPLD + (w + 1)] = acc[j];

  // halo zeroing for this block's 4 channel planes
  if (threadIdx.x < 32) {
    int ch = threadIdx.x >> 3;
    int rw = (threadIdx.x >> 1) & 3;
    int side = threadIdx.x & 1;
    plane[(size_t)ch * CPCH + (hq * 4 + rw + 1) * CPLD + side * 65] = 0.f;
  }
  if (hq == 0)
    for (int i = threadIdx.x; i < 4 * CPLD; i += 256)
      plane[(size_t)(i / CPLD) * CPCH + (i % CPLD)] = 0.f;               // top row
  if (hq == 15)
    for (int i = threadIdx.x; i < 4 * CPLD; i += 256)
      plane[(size_t)(i / CPLD) * CPCH + 65 * CPLD + (i % CPLD)] = 0.f;   // bottom row
}

// ------------- k2: fused 3x3 convs comp_pad -> off(8ch) + ker(25ch) -------------
// 544 blocks: (n, ocp of 17, hq of 16). 2 oc/thread; reg tile t[4][9]; uniform s_load weights.
__global__ __launch_bounds__(256) void k2_conv3(const float* __restrict__ comp_pad,
                                                const float* __restrict__ w_off,
                                                const float* __restrict__ b_off,
                                                const float* __restrict__ w_ker,
                                                const float* __restrict__ b_ker,
                                                float* __restrict__ offb,
                                                float* __restrict__ kerb) {
  int b = blockIdx.x;
  int n = b / (17 * 16);
  int r = b % (17 * 16);
  int ocp = r / 16;
  int hq = r % 16;
  int hsub = threadIdx.x >> 6;
  int w = threadIdx.x & 63;
  int h = hq * 4 + hsub;

  int oc0 = ocp * 2;
  int oc1 = (oc0 + 1 < 33) ? oc0 + 1 : 32;
  const float* wp0 = (oc0 < 8) ? (w_off + (size_t)oc0 * CCMP * 9)
                               : (w_ker + (size_t)(oc0 - 8) * CCMP * 9);
  const float* wp1 = (oc1 < 8) ? (w_off + (size_t)oc1 * CCMP * 9)
                               : (w_ker + (size_t)(oc1 - 8) * CCMP * 9);
  float a0 = (oc0 < 8) ? b_off[oc0] : b_ker[oc0 - 8];
  float a1 = (oc1 < 8) ? b_off[oc1] : b_ker[oc1 - 8];

  const float* base = comp_pad + (size_t)n * CPIMG + h * CPLD + w;

  for (int cb = 0; cb < CCMP; cb += 4) {
    float t[4][9];
#pragma unroll
    for (int cc = 0; cc < 4; ++cc) {
      const float* p = base + (size_t)(cb + cc) * CPCH;
#pragma unroll
      for (int dy = 0; dy < 3; ++dy)
#pragma unroll
        for (int dx = 0; dx < 3; ++dx)
          t[cc][dy * 3 + dx] = p[dy * CPLD + dx];
    }
#pragma unroll
    for (int cc = 0; cc < 4; ++cc)
#pragma unroll
      for (int k = 0; k < 9; ++k) {
        float tv = t[cc][k];
        a0 += tv * wp0[(cb + cc) * 9 + k];
        a1 += tv * wp1[(cb + cc) * 9 + k];
      }
  }

  int pos = h * WW + w;
  if (oc0 < 8) offb[(size_t)(n * 8 + oc0) * 4096 + pos] = a0;
  else         kerb[(size_t)(n * 25 + (oc0 - 8)) * 4096 + pos] = a0;
  if (oc1 < 8) offb[(size_t)(n * 8 + oc1) * 4096 + pos] = a1;
  else         kerb[(size_t)(n * 25 + (oc1 - 8)) * 4096 + pos] = a1;
}

// ------- k34: fused softmax + bilinear sample -> wts[n][h][pq][k][w] -------
// 512 blocks x 64 threads (2 blocks/CU). kerb holds RAW conv outputs.
__global__ __launch_bounds__(64, 2) void k34_wts(const float* __restrict__ offb,
                                                 const float* __restrict__ kerb,
                                                 float* __restrict__ wts) {
  int t = blockIdx.x * 64 + threadIdx.x;    // 32768 threads: (n, ho, wo)
  int n = t >> 14;
  int r = t & 16383;
  int ho = r >> 7;
  int wo = r & 127;
  int h = ho >> 1, p = ho & 1, w = wo >> 1, q = wo & 1;
  int pq = p * 2 + q;
  float offx = offb[((size_t)(n * 8 + pq) * HH + h) * WW + w];
  float offy = offb[((size_t)(n * 8 + 4 + pq) * HH + h) * WW + w];
  // align_corners=True + border clamp algebra: sample at (h+offy, w+offx)
  float ix = fminf(fmaxf((float)w + offx, 0.f), 63.f);
  float iy = fminf(fmaxf((float)h + offy, 0.f), 63.f);
  float x0f = floorf(ix), y0f = floorf(iy);
  float fx = ix - x0f, fy = iy - y0f;
  int x0 = (int)x0f, y0 = (int)y0f;
  int x1 = min(x0 + 1, 63), y1 = min(y0 + 1, 63);
  float g0 = (1.f - fx) * (1.f - fy), g1 = fx * (1.f - fy);
  float g2 = (1.f - fx) * fy,         g3 = fx * fy;

  const float* mb = kerb + (size_t)n * 25 * 4096;
  int c0 = y0 * 64 + x0, c1 = y0 * 64 + x1, c2 = y1 * 64 + x0, c3 = y1 * 64 + x1;

  float v0[25], v1[25], v2[25], v3[25];
#pragma unroll
  for (int k = 0; k < 25; ++k) {
    const float* mk = mb + (size_t)k * 4096;
    v0[k] = mk[c0]; v1[k] = mk[c1]; v2[k] = mk[c2]; v3[k] = mk[c3];
  }
  float m0 = v0[0], m1 = v1[0], m2 = v2[0], m3 = v3[0];
#pragma unroll
  for (int k = 1; k < 25; ++k) {
    m0 = fmaxf(m0, v0[k]); m1 = fmaxf(m1, v1[k]);
    m2 = fmaxf(m2, v2[k]); m3 = fmaxf(m3, v3[k]);
  }
  float S0 = 0.f, S1 = 0.f, S2 = 0.f, S3 = 0.f;
#pragma unroll
  for (int k = 0; k < 25; ++k) {
    v0[k] = expf(v0[k] - m0); S0 += v0[k];
    v1[k] = expf(v1[k] - m1); S1 += v1[k];
    v2[k] = expf(v2[k] - m2); S2 += v2[k];
    v3[k] = expf(v3[k] - m3); S3 += v3[k];
  }
  float f0 = g0 / S0, f1 = g1 / S1, f2 = g2 / S2, f3 = g3 / S3;

  float* wp = wts + (((size_t)(n * HH + h) * 4 + pq) * 25) * 64 + w;
#pragma unroll
  for (int k = 0; k < 25; ++k)
    wp[k * 64] = v0[k] * f0 + v1[k] * f1 + v2[k] * f2 + v3[k] * f3;
}

// -------- k5: all 4 outputs per tap pass; wt[100] hoisted; cap 256 VGPR (no spill) --------
__global__ __launch_bounds__(256, 2) void k5_out(const float* __restrict__ x,
                                                 const float* __restrict__ wts,
                                                 float* __restrict__ out) {
  int b = blockIdx.x;       // 1024 blocks: n(2) * h(64) * cg(8)
  int n = b >> 9;
  int r = b & 511;
  int h = r >> 3;
  int cg = r & 7;
  int wave = threadIdx.x >> 6;
  int w = threadIdx.x & 63;
  int c0 = cg * 32 + wave * 8;   // 8 channels per wave

  // hoist all 100 weights; coalesced (lane w fastest in wts layout)
  const float* wbase = wts + (size_t)(n * HH + h) * 100 * 64 + w;
  float wt[100];
#pragma unroll
  for (int i = 0; i < 100; ++i) wt[i] = wbase[i * 64];

  for (int ci = 0; ci < 8; ++ci) {
    int c = c0 + ci;
    const float* xc = x + (size_t)(n * CIN + c) * HH * WW;
    float a0 = 0.f, a1 = 0.f, a2 = 0.f, a3 = 0.f;
#pragma unroll
    for (int dy = 0; dy < 5; ++dy) {
      int rr = h + dy - 2;
      bool rok = (unsigned)rr < (unsigned)HH;
      const float* xr = xc + rr * WW;
#pragma unroll
      for (int dx = 0; dx < 5; ++dx) {
        int cc = w + dx - 2;
        float xv = (rok && (unsigned)cc < (unsigned)WW) ? xr[cc] : 0.f;
        int k = dy * 5 + dx;
        a0 += wt[k] * xv;
        a1 += wt[25 + k] * xv;
        a2 += wt[50 + k] * xv;
        a3 += wt[75 + k] * xv;
      }
    }
    float* o0 = out + ((size_t)(n * CIN + c) * HO + 2 * h) * WO + 2 * w;
    *(float2*)o0 = make_float2(a0, a1);
    *(float2*)(o0 + WO) = make_float2(a2, a3);
  }
}

extern "C" void kernel_launch(void* const* d_in, const int* in_sizes, int n_in,
                              void* d_out, int out_size, void* d_ws, size_t ws_size,
                              hipStream_t stream) {
  const float* x      = (const float*)d_in[0];
  const float* w_comp = (const float*)d_in[1];
  const float* b_comp = (const float*)d_in[2];
  const float* w_off  = (const float*)d_in[3];
  const float* b_off  = (const float*)d_in[4];
  const float* w_ker  = (const float*)d_in[5];
  const float* b_ker  = (const float*)d_in[6];
  float* out = (float*)d_out;

  float* ws       = (float*)d_ws;
  float* comp_pad = ws;
  float* offb     = ws + OFF_OFFB;
  float* kerb     = ws + OFF_KERB;   // raw conv output (softmax fused into k34)
  float* wts      = ws + OFF_WTS;

  k1_comp<<<512, 256, 0, stream>>>(x, w_comp, b_comp, comp_pad);
  k2_conv3<<<544, 256, 0, stream>>>(comp_pad, w_off, b_off, w_ker, b_ker, offb, kerb);
  k34_wts<<<512, 64, 0, stream>>>(offb, kerb, wts);
  k5_out<<<1024, 256, 0, stream>>>(x, wts, out);
}